// Round 9
// baseline (179.913 us; speedup 1.0000x reference)
//
#include <hip/hip_runtime.h>

// DynamicDilationUnfold: B=4, C=64, H=W=128, G=4, Cg=16, K=3, stride=1, pad=1.
// out[b][((g*Cg+cg)*K+kh)*K+kw][ho*Wo+wo], fp32.
//
// R13: store-instruction-count A/B at FULL occupancy ("R6 done right").
// Exonerated so far (normalized kernel us): read path (R4=R5=76), occupancy
// (saturates >=24w), run length 256B..16KiB (R8=74.7), sequential plane
// regions (R10 worse, confounded by 2x instrs), nt policy (R12 neutral).
// Last untested store variable: instruction count at 32 waves/CU. R10 slope:
// +294K wave-stores ~ +13us -> halving should save ~6-8us.
//   - tile 8x128, CPB=2, 256 thr, 4 wo/thread -> 18 dwordx4 stores/thread
//     (0.25 instrs/element, half of R8); wave store = 1 KiB over 2 rows
//   - 15.1 KB LDS -> 8 blocks/CU x 4 waves = 32 waves/CU; launch_bounds
//     (256,8) = 64-VGPR cap (R8-proven body budget)
//   - DS per element unchanged (2x ds_read2); weights shared across 2 ch
// Prediction: kernel ~67-70 (graded ~156-159) if store-count matters;
// neutral (~164) -> full store matrix flat -> structural wall, declare.

constexpr int B  = 4;
constexpr int C  = 64;
constexpr int H  = 128;
constexpr int W  = 128;
constexpr int G  = 4;
constexpr int Cg = C / G;            // 16
constexpr int K  = 3;
constexpr int KK = K * K;
constexpr int Ho = 128;
constexpr int Wo = 128;
constexpr int HW = H * W;
constexpr int HoWo = Ho * Wo;

constexpr int TILE_H = 8;            // rows per block, full 128-col width
constexpr int CPB    = 2;            // channels per block
constexpr int REG_H  = 14;           // image rows ro0-1 .. ro0+12 (ph_reg<13)
constexpr int REG_W  = 134;          // image cols -1 .. 132    (pw_reg<133)
constexpr int LDS_STRIDE = 135;      // odd stride -> bank-decorrelated
constexpr int CH_STRIDE  = REG_H * LDS_STRIDE;   // 1890 dwords per channel
constexpr int NSTAGE     = CPB * CH_STRIDE;      // 3780 dwords = 15,120 B
constexpr int NTHREADS   = 256;

__global__ __launch_bounds__(NTHREADS, 8) void ddu_kernel(
    const float* __restrict__ x,      // (B, C, H, W)
    const float* __restrict__ dmap,   // (B, G, H, W)
    float* __restrict__ out)          // (B, C*K*K, Ho*Wo)
{
    __shared__ float lds[NSTAGE];                // 15,120 B -> 8 blocks/CU

    const int tid = threadIdx.x;
    const int bid = blockIdx.x;                  // 2048 = b(4) g(4) chunk(8) rt(16)
    const int rt    = bid & 15;
    const int chunk = (bid >> 4) & 7;
    const int g     = (bid >> 7) & 3;
    const int b     = bid >> 9;

    const int ro0 = rt * TILE_H;
    const int cgb = chunk * CPB;

    const float* __restrict__ xg = x + (size_t)(b * C + g * Cg + cgb) * HW;

    // ---- stage: channel-planar scalar LDS, coalesced dword loads, zero halo ----
#pragma unroll
    for (int it = 0; it < (NSTAGE + NTHREADS - 1) / NTHREADS; ++it) {
        const int p = it * NTHREADS + tid;
        if (p < NSTAGE) {
            const int ch  = p / CH_STRIDE;
            const int rem = p - ch * CH_STRIDE;
            const int rr  = rem / LDS_STRIDE;
            const int cc  = rem - rr * LDS_STRIDE;
            const int ir  = ro0 - 1 + rr;
            const int ic  = cc - 1;
            float v = 0.f;
            if ((unsigned)ir < (unsigned)H && (unsigned)ic < (unsigned)W && cc < REG_W)
                v = xg[(size_t)ch * HW + ir * W + ic];
            lds[p] = v;                          // zero halo == validity mask
        }
    }
    __syncthreads();

    // ---- compute: each thread owns 4 adjacent wo; wave = 2 full rows ----
    const int wi4 = tid & 31;                    // 0..31 -> wo block of 4
    const int hi  = tid >> 5;                    // 0..7
    const int ho  = ro0 + hi;
    const int wo  = wi4 * 4;

    const float4 dq = *(const float4*)&dmap[(size_t)(b * G + g) * HoWo + ho * Wo + wo];
    const float dd[4] = { dq.x, dq.y, dq.z, dq.w };

    float* __restrict__ outb = out
        + (size_t)((b * C + g * Cg + cgb) * KK) * HoWo
        + (size_t)(ho * Wo + wo);

    const float rowf = (float)hi;                // region row coordinate base

#pragma unroll
    for (int kh = 0; kh < K; ++kh) {
        int   rr_[4];
        float lh_[4], mh_[4];
#pragma unroll
        for (int sp = 0; sp < 4; ++sp) {
            const float ph = rowf + (float)kh * dd[sp];   // region row coord
            const int   r  = (int)ph;                     // 0..12
            rr_[sp] = r;
            lh_[sp] = ph - (float)r;
            mh_[sp] = 1.f - lh_[sp];
        }

#pragma unroll
        for (int kw = 0; kw < K; ++kw) {
            int   base_[4];
            float a00_[4], a01_[4], a10_[4], a11_[4];
#pragma unroll
            for (int sp = 0; sp < 4; ++sp) {
                const float pw = (float)(wo + sp) + (float)kw * dd[sp];  // region col
                const int   c  = (int)pw;                 // 0..132
                const float lw = pw - (float)c;
                base_[sp] = rr_[sp] * LDS_STRIDE + c;
                a00_[sp] = mh_[sp] * (1.f - lw);
                a01_[sp] = mh_[sp] * lw;
                a10_[sp] = lh_[sp] * (1.f - lw);
                a11_[sp] = lh_[sp] * lw;
            }

            float* __restrict__ o = outb + (size_t)(kh * K + kw) * HoWo;

#pragma unroll
            for (int ch = 0; ch < CPB; ++ch) {
                const float* __restrict__ l = lds + ch * CH_STRIDE;
                float4 v;
                {
                    const float* __restrict__ p0 = l + base_[0];
                    v.x = a00_[0] * p0[0] + a01_[0] * p0[1]
                        + a10_[0] * p0[LDS_STRIDE] + a11_[0] * p0[LDS_STRIDE + 1];
                }
                {
                    const float* __restrict__ p1 = l + base_[1];
                    v.y = a00_[1] * p1[0] + a01_[1] * p1[1]
                        + a10_[1] * p1[LDS_STRIDE] + a11_[1] * p1[LDS_STRIDE + 1];
                }
                {
                    const float* __restrict__ p2 = l + base_[2];
                    v.z = a00_[2] * p2[0] + a01_[2] * p2[1]
                        + a10_[2] * p2[LDS_STRIDE] + a11_[2] * p2[LDS_STRIDE + 1];
                }
                {
                    const float* __restrict__ p3 = l + base_[3];
                    v.w = a00_[3] * p3[0] + a01_[3] * p3[1]
                        + a10_[3] * p3[LDS_STRIDE] + a11_[3] * p3[LDS_STRIDE + 1];
                }
                *(float4*)(o + (size_t)ch * (KK * HoWo)) = v;   // 16 B/lane, 1 KiB/wave
            }
        }
    }
}

extern "C" void kernel_launch(void* const* d_in, const int* in_sizes, int n_in,
                              void* d_out, int out_size, void* d_ws, size_t ws_size,
                              hipStream_t stream) {
    const float* x    = (const float*)d_in[0];
    const float* dmap = (const float*)d_in[1];
    float* out = (float*)d_out;

    const int grid = B * G * (Cg / CPB) * (Ho / TILE_H);   // 2048 = 8 blocks/CU
    ddu_kernel<<<grid, NTHREADS, 0, stream>>>(x, dmap, out);
}